// Round 6
// baseline (304.956 us; speedup 1.0000x reference)
//
#include <hip/hip_runtime.h>

#define N_NODES   100000
#define N_EDGES   1600000
#define D         128
#define NUM_GRAPHS 128

#define NB          196     // dst buckets (512 nodes each): 99999>>9 = 195
#define BUCKET_NODES 512
#define BUCKET_CAP  10240   // >= bucket edge count w/ huge margin (mean 8163, sd 90)
#define EPB         8192    // edges per binplace block

#define GEMM_WAVES  2048    // 512 blocks x 4 waves
#define N_CHUNKS    3125    // 100000 / 32 exactly

typedef __attribute__((ext_vector_type(8))) short   bf16x8;
typedef __attribute__((ext_vector_type(8))) unsigned short u16x8;
typedef __attribute__((ext_vector_type(4))) float   f32x4;

__device__ __forceinline__ float bf2f(unsigned short v) {
    return __uint_as_float(((unsigned int)v) << 16);
}
__device__ __forceinline__ unsigned short f2bf(float f) {
    unsigned int u = __float_as_uint(f);
    u = (u + 0x7FFFu + ((u >> 16) & 1u)) >> 16;
    return (unsigned short)u;
}

// ---------------- edge binning: counting-sort into 196 bucket regions ----------------
__global__ __launch_bounds__(256) void k_binplace(const int* __restrict__ src,
                                                  const int* __restrict__ dst,
                                                  int* __restrict__ gcur,
                                                  unsigned int* __restrict__ binned) {
    __shared__ unsigned int stag[EPB];       // 32 KB
    __shared__ unsigned char sbk[EPB];       // 8 KB
    __shared__ int hist[NB], lstart[NB], lcur[NB], gclaim[NB];
    __shared__ int scan[256];
    const int t = threadIdx.x;
    const int e0 = blockIdx.x * EPB;

    if (t < NB) hist[t] = 0;
    __syncthreads();

    int pk[32]; int bk[32];
#pragma unroll
    for (int i = 0; i < 32; ++i) {
        int e = e0 + t + 256 * i;
        if (e < N_EDGES) {
            int s = src[e], d = dst[e];
            bk[i] = d >> 9;
            pk[i] = (s << 9) | (d & 511);
            atomicAdd(&hist[bk[i]], 1);
        } else {
            bk[i] = -1; pk[i] = 0;
        }
    }
    __syncthreads();

    int hv = (t < NB) ? hist[t] : 0;
    scan[t] = hv;
    __syncthreads();
    for (int off = 1; off < 256; off <<= 1) {
        int add = (t >= off) ? scan[t - off] : 0;
        __syncthreads();
        scan[t] += add;
        __syncthreads();
    }
    if (t < NB) {
        int ex = scan[t] - hv;
        lstart[t] = ex;
        lcur[t]   = ex;
        gclaim[t] = atomicAdd(&gcur[t], hv);
    }
    __syncthreads();

#pragma unroll
    for (int i = 0; i < 32; ++i) {
        if (bk[i] >= 0) {
            int p = atomicAdd(&lcur[bk[i]], 1);
            stag[p] = (unsigned int)pk[i];
            sbk[p] = (unsigned char)bk[i];
        }
    }
    __syncthreads();

    const int total = scan[NB - 1];
    for (int j = t; j < total; j += 256) {
        int b = sbk[j];
        binned[(size_t)b * BUCKET_CAP + gclaim[b] + (j - lstart[b])] = stag[j];
    }
}

// ---------------- per-bucket CSR finalize ----------------
__global__ __launch_bounds__(256) void k_fill2(const unsigned int* __restrict__ binned,
                                               const int* __restrict__ gcur,
                                               int* __restrict__ adj,
                                               int* __restrict__ row_start,
                                               int* __restrict__ row_len) {
    __shared__ int hist[BUCKET_NODES], lstart[BUCKET_NODES], lcur[BUCKET_NODES];
    __shared__ int s2[256];
    const int t = threadIdx.x;
    const int b = blockIdx.x;
    const int C = gcur[b];
    const unsigned int* bp = binned + (size_t)b * BUCKET_CAP;

    hist[t] = 0; hist[t + 256] = 0;
    __syncthreads();
    for (int j = t; j < C; j += 256)
        atomicAdd(&hist[bp[j] & 511], 1);
    __syncthreads();

    int h0 = hist[2 * t], h1 = hist[2 * t + 1];
    int sv = h0 + h1;
    s2[t] = sv;
    __syncthreads();
    for (int off = 1; off < 256; off <<= 1) {
        int add = (t >= off) ? s2[t - off] : 0;
        __syncthreads();
        s2[t] += add;
        __syncthreads();
    }
    int ex = s2[t] - sv;
    lstart[2 * t] = ex;          lcur[2 * t] = ex;
    lstart[2 * t + 1] = ex + h0; lcur[2 * t + 1] = ex + h0;
    __syncthreads();

    for (int dl = t; dl < BUCKET_NODES; dl += 256) {
        int n = b * BUCKET_NODES + dl;
        if (n < N_NODES) {
            row_start[n] = b * BUCKET_CAP + lstart[dl];
            row_len[n]   = hist[dl];
        }
    }

    for (int j = t; j < C; j += 256) {
        unsigned int v = bp[j];
        int dl = v & 511;
        int pos = atomicAdd(&lcur[dl], 1);
        adj[(size_t)b * BUCKET_CAP + pos] = (int)(v >> 9);
    }
}

// graph_ids is SORTED -> per-graph count via binary search, no atomics.
__global__ void k_gcnt_bs(const int* __restrict__ gid, int* __restrict__ gcnt) {
    int g = threadIdx.x;
    if (g >= NUM_GRAPHS) return;
    int lo = 0, hi = N_NODES;
    while (lo < hi) { int mid = (lo + hi) >> 1; if (gid[mid] < g) lo = mid + 1; else hi = mid; }
    int beg = lo;
    hi = N_NODES;
    while (lo < hi) { int mid = (lo + hi) >> 1; if (gid[mid] < g + 1) lo = mid + 1; else hi = mid; }
    gcnt[g] = lo - beg;
}

// ---------------- casts / weight prep ----------------

__global__ void k_cast_h(const float* __restrict__ h, unsigned short* __restrict__ hb) {
    int i = blockIdx.x * 256 + threadIdx.x;          // one thread = 8 elems
    if (i >= N_NODES * (D / 8)) return;
    const float4* hv = (const float4*)h;
    float4 x = hv[2 * i], y = hv[2 * i + 1];
    u16x8 p;
    p[0] = f2bf(x.x); p[1] = f2bf(x.y); p[2] = f2bf(x.z); p[3] = f2bf(x.w);
    p[4] = f2bf(y.x); p[5] = f2bf(y.y); p[6] = f2bf(y.z); p[7] = f2bf(y.w);
    *(u16x8*)(hb + (size_t)i * 8) = p;
}

// Fragment-linear weight prep:
//   Wtp[((ct*8+ks)*64 + lane)*8 + j] = W[k][n],  n = ct*16+(lane&15),
//   k = ks*32 + 8*(lane>>4) + j.  (k<128 -> Ws, else Wn at k-128)
__global__ void k_prep_w1(const float* __restrict__ Ws, const float* __restrict__ Wn,
                          unsigned short* __restrict__ Wtp) {
    int idx = blockIdx.x * 256 + threadIdx.x;  // 32768
    if (idx >= D * 256) return;
    int j  = idx & 7;
    int l  = (idx >> 3) & 63;
    int fs = idx >> 9;               // ct*8 + ks
    int ct = fs >> 3, ks = fs & 7;
    int n  = ct * 16 + (l & 15);
    int k  = ks * 32 + 8 * (l >> 4) + j;
    float v = (k < 128) ? Ws[k * D + n] : Wn[(k - 128) * D + n];
    Wtp[idx] = f2bf(v);
}

// Same, but layer-1 output columns are stored permuted:
//   h1p[row][(col&15)*8 + (col>>4)] = h1[row][col]
__global__ void k_prep_w2(const float* __restrict__ Ws, const float* __restrict__ Wn,
                          unsigned short* __restrict__ Wtp) {
    int idx = blockIdx.x * 256 + threadIdx.x;  // 32768
    if (idx >= D * 256) return;
    int j  = idx & 7;
    int l  = (idx >> 3) & 63;
    int fs = idx >> 9;
    int ct = fs >> 3, ks = fs & 7;
    int n  = ct * 16 + (l & 15);
    int kp = ks * 32 + 8 * (l >> 4) + j;
    int kk = kp & 127;
    int col = (kk & 7) * 16 + (kk >> 3);
    float v = (kp < 128) ? Ws[col * D + n] : Wn[col * D + n];
    Wtp[idx] = f2bf(v);
}

// ---------------- mean aggregation, bf16 gather (16 threads / node) ----------------
__global__ __launch_bounds__(256) void k_agg_bf(const unsigned short* __restrict__ hin,
                                                const int* __restrict__ row_start,
                                                const int* __restrict__ row_len,
                                                const int* __restrict__ adj,
                                                unsigned short* __restrict__ hout) {
    int node = blockIdx.x * 16 + (threadIdx.x >> 4);
    int sub = threadIdx.x & 15;                      // owns 8 bf16 = 16 B of the row
    if (node >= N_NODES) return;
    int beg = row_start[node];
    int len = row_len[node];
    int end = beg + len;
    float acc[8];
#pragma unroll
    for (int i = 0; i < 8; ++i) acc[i] = 0.f;
    int j = beg;
    for (; j + 1 < end; j += 2) {
        int s0 = adj[j], s1 = adj[j + 1];
        u16x8 v0 = *(const u16x8*)(hin + (size_t)s0 * D + sub * 8);
        u16x8 v1 = *(const u16x8*)(hin + (size_t)s1 * D + sub * 8);
#pragma unroll
        for (int i = 0; i < 8; ++i) acc[i] += bf2f(v0[i]) + bf2f(v1[i]);
    }
    if (j < end) {
        int s0 = adj[j];
        u16x8 v0 = *(const u16x8*)(hin + (size_t)s0 * D + sub * 8);
#pragma unroll
        for (int i = 0; i < 8; ++i) acc[i] += bf2f(v0[i]);
    }
    float inv = (len > 0) ? 1.f / (float)len : 0.f;
    u16x8 p;
#pragma unroll
    for (int i = 0; i < 8; ++i) p[i] = f2bf(acc[i] * inv);
    *(u16x8*)(hout + (size_t)node * D + sub * 8) = p;
}

// ---------------- pipelined MFMA GEMM: stage W once, waves free-run ----------------
// 512 blocks x 4 waves. W (64 KB) staged to LDS once, ONE barrier. Then each of
// the 2048 waves processes up to 2 independent 32-row chunks (3125 total) with a
// register double-buffer: chunk2's A-loads are issued BEFORE chunk1's MFMA phase,
// so (in-order vmcnt) they stay in flight during compute. No steady-state barriers.
template <int POOL>
__global__ __launch_bounds__(256) void k_gemm_mfma(
    const unsigned short* __restrict__ X0, const unsigned short* __restrict__ X1,
    const unsigned short* __restrict__ Wtp, const float* __restrict__ bias,
    unsigned short* __restrict__ outp,
    const int* __restrict__ gid, float* __restrict__ gsum) {
    __shared__ unsigned short WS[D * 256];   // 64 KB
    const int tid = threadIdx.x;
    const int wave = tid >> 6, lane = tid & 63;
    const int lm = lane & 15, lg = lane >> 4;
    const int koff = 8 * lg;
    const int gw = blockIdx.x * 4 + wave;    // 0..2047

    // stage weights -> LDS (one-time)
    {
        const u16x8* g = (const u16x8*)Wtp;
        u16x8* s = (u16x8*)WS;
#pragma unroll
        for (int i = 0; i < 16; ++i) s[i * 256 + tid] = g[i * 256 + tid];
    }

    // A fragments, chunk 1 (issued before the barrier; drained by it anyway)
    bf16x8 a0[2][8], a1[2][8];
    const int c0 = gw;
#pragma unroll
    for (int t2 = 0; t2 < 2; ++t2) {
        int arow = c0 * 32 + t2 * 16 + lm;
#pragma unroll
        for (int ks = 0; ks < 4; ++ks)
            a0[t2][ks] = *(const bf16x8*)(X0 + (size_t)arow * D + ks * 32 + koff);
#pragma unroll
        for (int ks = 0; ks < 4; ++ks)
            a0[t2][4 + ks] = *(const bf16x8*)(X1 + (size_t)arow * D + ks * 32 + koff);
    }
    __syncthreads();

    const int c1 = gw + GEMM_WAVES;
    const bool has2 = (c1 < N_CHUNKS);
    if (has2) {
#pragma unroll
        for (int t2 = 0; t2 < 2; ++t2) {
            int arow = c1 * 32 + t2 * 16 + lm;
#pragma unroll
            for (int ks = 0; ks < 4; ++ks)
                a1[t2][ks] = *(const bf16x8*)(X0 + (size_t)arow * D + ks * 32 + koff);
#pragma unroll
            for (int ks = 0; ks < 4; ++ks)
                a1[t2][4 + ks] = *(const bf16x8*)(X1 + (size_t)arow * D + ks * 32 + koff);
        }
    }

#pragma unroll 1
    for (int pass = 0; pass < 2; ++pass) {
        if (pass == 1 && !has2) break;
        const int chunk = (pass == 0) ? c0 : c1;
        bf16x8 (&a)[2][8] = (pass == 0) ? a0 : a1;

        f32x4 acc[2][8];
#pragma unroll
        for (int t2 = 0; t2 < 2; ++t2)
#pragma unroll
            for (int i = 0; i < 8; ++i) acc[t2][i] = (f32x4){0.f, 0.f, 0.f, 0.f};

#pragma unroll
        for (int ct = 0; ct < 8; ++ct) {
            bf16x8 b[8];
#pragma unroll
            for (int ks = 0; ks < 8; ++ks)
                b[ks] = *(const bf16x8*)&WS[((ct * 8 + ks) * 64 + lane) * 8];
#pragma unroll
            for (int ks = 0; ks < 8; ++ks) {
                acc[0][ct] = __builtin_amdgcn_mfma_f32_16x16x32_bf16(a[0][ks], b[ks], acc[0][ct], 0, 0, 0);
                acc[1][ct] = __builtin_amdgcn_mfma_f32_16x16x32_bf16(a[1][ks], b[ks], acc[1][ct], 0, 0, 0);
            }
        }

#pragma unroll
        for (int t2 = 0; t2 < 2; ++t2) {
            const int trow0 = chunk * 32 + t2 * 16;
            if (POOL == 0) {
#pragma unroll
                for (int r = 0; r < 4; ++r) {
                    int row = trow0 + 4 * lg + r;
                    u16x8 pk;
#pragma unroll
                    for (int ct = 0; ct < 8; ++ct) {
                        float v = acc[t2][ct][r] + bias[ct * 16 + lm];
                        pk[ct] = f2bf(fmaxf(v, 0.f));
                    }
                    *(u16x8*)(outp + (size_t)row * D + lm * 8) = pk;
                }
            } else {
                int g[4];
#pragma unroll
                for (int r = 0; r < 4; ++r)
                    g[r] = gid[trow0 + 4 * lg + r];
#pragma unroll
                for (int ct = 0; ct < 8; ++ct) {
                    int c = ct * 16 + lm;
                    float bia = bias[c];
                    float run = 0.f; int curg = -1;
#pragma unroll
                    for (int r = 0; r < 4; ++r) {
                        float v = fmaxf(acc[t2][ct][r] + bia, 0.f);
                        if (g[r] != curg) {
                            if (curg >= 0) atomicAdd(&gsum[curg * D + c], run);
                            curg = g[r]; run = v;
                        } else {
                            run += v;
                        }
                    }
                    if (curg >= 0) atomicAdd(&gsum[curg * D + c], run);
                }
            }
        }
    }
}

// ---------------- final divide ----------------
__global__ void k_final(const float* __restrict__ gsum, const int* __restrict__ gcnt,
                        float* __restrict__ out) {
    int i = blockIdx.x * blockDim.x + threadIdx.x;
    if (i < NUM_GRAPHS * D) {
        int g = i >> 7;
        int c = gcnt[g];
        out[i] = gsum[i] / (float)(c > 0 ? c : 1);
    }
}

// ---------------- launch ----------------
extern "C" void kernel_launch(void* const* d_in, const int* in_sizes, int n_in,
                              void* d_out, int out_size, void* d_ws, size_t ws_size,
                              hipStream_t stream) {
    const float* h   = (const float*)d_in[0];
    const float* W1s = (const float*)d_in[1];
    const float* W1n = (const float*)d_in[2];
    const float* b1  = (const float*)d_in[3];
    const float* W2s = (const float*)d_in[4];
    const float* W2n = (const float*)d_in[5];
    const float* b2  = (const float*)d_in[6];
    const int* src   = (const int*)d_in[7];
    const int* dst   = (const int*)d_in[8];
    const int* gids  = (const int*)d_in[9];
    float* out = (float*)d_out;
    char* ws = (char*)d_ws;

    size_t off = 0;
    auto alloc = [&](size_t bytes) {
        size_t o = off;
        off = (off + bytes + 255) & ~(size_t)255;
        return o;
    };
    // zeroed region (one memset)
    size_t z0         = off;
    size_t gcur_off   = alloc((size_t)NB * 4);
    size_t gsum_off   = alloc((size_t)NUM_GRAPHS * D * 4);
    size_t zlen       = off - z0;
    size_t gcnt_off   = alloc((size_t)NUM_GRAPHS * 4);
    size_t rs_off     = alloc((size_t)N_NODES * 4);
    size_t rl_off     = alloc((size_t)N_NODES * 4);
    size_t bin_off    = alloc((size_t)NB * BUCKET_CAP * 4);
    size_t adj_off    = alloc((size_t)NB * BUCKET_CAP * 4);
    size_t hb_off     = alloc((size_t)N_NODES * D * 2);   // h bf16
    size_t hn_off     = alloc((size_t)N_NODES * D * 2);   // neigh agg bf16 (reused layer2)
    size_t h1_off     = alloc((size_t)N_NODES * D * 2);   // layer-1 out (permuted) bf16
    size_t wt1_off    = alloc((size_t)D * 256 * 2);
    size_t wt2_off    = alloc((size_t)D * 256 * 2);
    (void)ws_size;

    int*   gcur      = (int*)(ws + gcur_off);
    int*   gcnt      = (int*)(ws + gcnt_off);
    float* gsum      = (float*)(ws + gsum_off);
    int*   row_start = (int*)(ws + rs_off);
    int*   row_len   = (int*)(ws + rl_off);
    unsigned int* binned = (unsigned int*)(ws + bin_off);
    int*   adj       = (int*)(ws + adj_off);
    unsigned short* hb  = (unsigned short*)(ws + hb_off);
    unsigned short* hn  = (unsigned short*)(ws + hn_off);
    unsigned short* h1p = (unsigned short*)(ws + h1_off);
    unsigned short* Wt1 = (unsigned short*)(ws + wt1_off);
    unsigned short* Wt2 = (unsigned short*)(ws + wt2_off);

    hipMemsetAsync(ws + z0, 0, zlen, stream);

    const int nbin_blocks = (N_EDGES + EPB - 1) / EPB;   // 196

    k_binplace<<<nbin_blocks, 256, 0, stream>>>(src, dst, gcur, binned);
    k_fill2<<<NB, 256, 0, stream>>>(binned, gcur, adj, row_start, row_len);
    k_gcnt_bs<<<1, 128, 0, stream>>>(gids, gcnt);

    k_cast_h<<<(N_NODES * (D / 8) + 255) / 256, 256, 0, stream>>>(h, hb);
    k_prep_w1<<<(D * 256 + 255) / 256, 256, 0, stream>>>(W1s, W1n, Wt1);
    k_prep_w2<<<(D * 256 + 255) / 256, 256, 0, stream>>>(W2s, W2n, Wt2);

    const int gemm_blocks = GEMM_WAVES / 4;         // 512 (2 blocks/CU)
    const int agg_blocks  = (N_NODES + 15) / 16;    // 6250

    // layer 1
    k_agg_bf<<<agg_blocks, 256, 0, stream>>>(hb, row_start, row_len, adj, hn);
    k_gemm_mfma<0><<<gemm_blocks, 256, 0, stream>>>(hb, hn, Wt1, b1, h1p, nullptr, nullptr);
    // layer 2 (pool fused into epilogue)
    k_agg_bf<<<agg_blocks, 256, 0, stream>>>(h1p, row_start, row_len, adj, hn);
    k_gemm_mfma<1><<<gemm_blocks, 256, 0, stream>>>(h1p, hn, Wt2, b2, nullptr, gids, gsum);

    k_final<<<(NUM_GRAPHS * D + 255) / 256, 256, 0, stream>>>(gsum, gcnt, out);
}

// Round 7
// 284.201 us; speedup vs baseline: 1.0730x; 1.0730x over previous
//
#include <hip/hip_runtime.h>

#define N_NODES   100000
#define N_EDGES   1600000
#define D         128
#define NUM_GRAPHS 128

#define NB          196     // dst buckets (512 nodes each): 99999>>9 = 195
#define BUCKET_NODES 512
#define BUCKET_CAP  10240   // >= bucket edge count w/ huge margin (mean 8163, sd 90)
#define EPB         8192    // edges per binplace block

#define N_CHUNKS    3125    // 100000 / 32 exactly
#define GEMM_BLOCKS 391     // 391 * 8 waves = 3128 >= 3125

typedef __attribute__((ext_vector_type(8))) short   bf16x8;
typedef __attribute__((ext_vector_type(8))) unsigned short u16x8;
typedef __attribute__((ext_vector_type(4))) float   f32x4;

__device__ __forceinline__ float bf2f(unsigned short v) {
    return __uint_as_float(((unsigned int)v) << 16);
}
__device__ __forceinline__ unsigned short f2bf(float f) {
    unsigned int u = __float_as_uint(f);
    u = (u + 0x7FFFu + ((u >> 16) & 1u)) >> 16;
    return (unsigned short)u;
}

// ---------------- edge binning: counting-sort into 196 bucket regions ----------------
__global__ __launch_bounds__(256) void k_binplace(const int* __restrict__ src,
                                                  const int* __restrict__ dst,
                                                  int* __restrict__ gcur,
                                                  unsigned int* __restrict__ binned) {
    __shared__ unsigned int stag[EPB];       // 32 KB
    __shared__ unsigned char sbk[EPB];       // 8 KB
    __shared__ int hist[NB], lstart[NB], lcur[NB], gclaim[NB];
    __shared__ int scan[256];
    const int t = threadIdx.x;
    const int e0 = blockIdx.x * EPB;

    if (t < NB) hist[t] = 0;
    __syncthreads();

    int pk[32]; int bk[32];
#pragma unroll
    for (int i = 0; i < 32; ++i) {
        int e = e0 + t + 256 * i;
        if (e < N_EDGES) {
            int s = src[e], d = dst[e];
            bk[i] = d >> 9;
            pk[i] = (s << 9) | (d & 511);
            atomicAdd(&hist[bk[i]], 1);
        } else {
            bk[i] = -1; pk[i] = 0;
        }
    }
    __syncthreads();

    int hv = (t < NB) ? hist[t] : 0;
    scan[t] = hv;
    __syncthreads();
    for (int off = 1; off < 256; off <<= 1) {
        int add = (t >= off) ? scan[t - off] : 0;
        __syncthreads();
        scan[t] += add;
        __syncthreads();
    }
    if (t < NB) {
        int ex = scan[t] - hv;
        lstart[t] = ex;
        lcur[t]   = ex;
        gclaim[t] = atomicAdd(&gcur[t], hv);
    }
    __syncthreads();

#pragma unroll
    for (int i = 0; i < 32; ++i) {
        if (bk[i] >= 0) {
            int p = atomicAdd(&lcur[bk[i]], 1);
            stag[p] = (unsigned int)pk[i];
            sbk[p] = (unsigned char)bk[i];
        }
    }
    __syncthreads();

    const int total = scan[NB - 1];
    for (int j = t; j < total; j += 256) {
        int b = sbk[j];
        binned[(size_t)b * BUCKET_CAP + gclaim[b] + (j - lstart[b])] = stag[j];
    }
}

// ---------------- per-bucket CSR finalize ----------------
__global__ __launch_bounds__(256) void k_fill2(const unsigned int* __restrict__ binned,
                                               const int* __restrict__ gcur,
                                               int* __restrict__ adj,
                                               int* __restrict__ row_start,
                                               int* __restrict__ row_len) {
    __shared__ int hist[BUCKET_NODES], lstart[BUCKET_NODES], lcur[BUCKET_NODES];
    __shared__ int s2[256];
    const int t = threadIdx.x;
    const int b = blockIdx.x;
    const int C = gcur[b];
    const unsigned int* bp = binned + (size_t)b * BUCKET_CAP;

    hist[t] = 0; hist[t + 256] = 0;
    __syncthreads();
    for (int j = t; j < C; j += 256)
        atomicAdd(&hist[bp[j] & 511], 1);
    __syncthreads();

    int h0 = hist[2 * t], h1 = hist[2 * t + 1];
    int sv = h0 + h1;
    s2[t] = sv;
    __syncthreads();
    for (int off = 1; off < 256; off <<= 1) {
        int add = (t >= off) ? s2[t - off] : 0;
        __syncthreads();
        s2[t] += add;
        __syncthreads();
    }
    int ex = s2[t] - sv;
    lstart[2 * t] = ex;          lcur[2 * t] = ex;
    lstart[2 * t + 1] = ex + h0; lcur[2 * t + 1] = ex + h0;
    __syncthreads();

    for (int dl = t; dl < BUCKET_NODES; dl += 256) {
        int n = b * BUCKET_NODES + dl;
        if (n < N_NODES) {
            row_start[n] = b * BUCKET_CAP + lstart[dl];
            row_len[n]   = hist[dl];
        }
    }

    for (int j = t; j < C; j += 256) {
        unsigned int v = bp[j];
        int dl = v & 511;
        int pos = atomicAdd(&lcur[dl], 1);
        adj[(size_t)b * BUCKET_CAP + pos] = (int)(v >> 9);
    }
}

// graph_ids is SORTED -> per-graph count via binary search, no atomics.
__global__ void k_gcnt_bs(const int* __restrict__ gid, int* __restrict__ gcnt) {
    int g = threadIdx.x;
    if (g >= NUM_GRAPHS) return;
    int lo = 0, hi = N_NODES;
    while (lo < hi) { int mid = (lo + hi) >> 1; if (gid[mid] < g) lo = mid + 1; else hi = mid; }
    int beg = lo;
    hi = N_NODES;
    while (lo < hi) { int mid = (lo + hi) >> 1; if (gid[mid] < g + 1) lo = mid + 1; else hi = mid; }
    gcnt[g] = lo - beg;
}

// ---------------- casts / weight prep ----------------

__global__ void k_cast_h(const float* __restrict__ h, unsigned short* __restrict__ hb) {
    int i = blockIdx.x * 256 + threadIdx.x;          // one thread = 8 elems
    if (i >= N_NODES * (D / 8)) return;
    const float4* hv = (const float4*)h;
    float4 x = hv[2 * i], y = hv[2 * i + 1];
    u16x8 p;
    p[0] = f2bf(x.x); p[1] = f2bf(x.y); p[2] = f2bf(x.z); p[3] = f2bf(x.w);
    p[4] = f2bf(y.x); p[5] = f2bf(y.y); p[6] = f2bf(y.z); p[7] = f2bf(y.w);
    *(u16x8*)(hb + (size_t)i * 8) = p;
}

// Fragment-linear weight prep:
//   Wtp[((ct*8+ks)*64 + lane)*8 + j] = W[k][n],  n = ct*16+(lane&15),
//   k = ks*32 + 8*(lane>>4) + j.  (k<128 -> Ws, else Wn at k-128)
__global__ void k_prep_w1(const float* __restrict__ Ws, const float* __restrict__ Wn,
                          unsigned short* __restrict__ Wtp) {
    int idx = blockIdx.x * 256 + threadIdx.x;  // 32768
    if (idx >= D * 256) return;
    int j  = idx & 7;
    int l  = (idx >> 3) & 63;
    int fs = idx >> 9;               // ct*8 + ks
    int ct = fs >> 3, ks = fs & 7;
    int n  = ct * 16 + (l & 15);
    int k  = ks * 32 + 8 * (l >> 4) + j;
    float v = (k < 128) ? Ws[k * D + n] : Wn[(k - 128) * D + n];
    Wtp[idx] = f2bf(v);
}

// Same, but layer-1 output columns are stored permuted:
//   h1p[row][(col&15)*8 + (col>>4)] = h1[row][col]
__global__ void k_prep_w2(const float* __restrict__ Ws, const float* __restrict__ Wn,
                          unsigned short* __restrict__ Wtp) {
    int idx = blockIdx.x * 256 + threadIdx.x;  // 32768
    if (idx >= D * 256) return;
    int j  = idx & 7;
    int l  = (idx >> 3) & 63;
    int fs = idx >> 9;
    int ct = fs >> 3, ks = fs & 7;
    int n  = ct * 16 + (l & 15);
    int kp = ks * 32 + 8 * (l >> 4) + j;
    int kk = kp & 127;
    int col = (kk & 7) * 16 + (kk >> 3);
    float v = (kp < 128) ? Ws[col * D + n] : Wn[col * D + n];
    Wtp[idx] = f2bf(v);
}

// ---------------- mean aggregation, bf16 gather (16 threads / node) ----------------
__global__ __launch_bounds__(256) void k_agg_bf(const unsigned short* __restrict__ hin,
                                                const int* __restrict__ row_start,
                                                const int* __restrict__ row_len,
                                                const int* __restrict__ adj,
                                                unsigned short* __restrict__ hout) {
    int node = blockIdx.x * 16 + (threadIdx.x >> 4);
    int sub = threadIdx.x & 15;                      // owns 8 bf16 = 16 B of the row
    if (node >= N_NODES) return;
    int beg = row_start[node];
    int len = row_len[node];
    int end = beg + len;
    float acc[8];
#pragma unroll
    for (int i = 0; i < 8; ++i) acc[i] = 0.f;
    int j = beg;
    for (; j + 1 < end; j += 2) {
        int s0 = adj[j], s1 = adj[j + 1];
        u16x8 v0 = *(const u16x8*)(hin + (size_t)s0 * D + sub * 8);
        u16x8 v1 = *(const u16x8*)(hin + (size_t)s1 * D + sub * 8);
#pragma unroll
        for (int i = 0; i < 8; ++i) acc[i] += bf2f(v0[i]) + bf2f(v1[i]);
    }
    if (j < end) {
        int s0 = adj[j];
        u16x8 v0 = *(const u16x8*)(hin + (size_t)s0 * D + sub * 8);
#pragma unroll
        for (int i = 0; i < 8; ++i) acc[i] += bf2f(v0[i]);
    }
    float inv = (len > 0) ? 1.f / (float)len : 0.f;
    u16x8 p;
#pragma unroll
    for (int i = 0; i < 8; ++i) p[i] = f2bf(acc[i] * inv);
    *(u16x8*)(hout + (size_t)node * D + sub * 8) = p;
}

// ---------------- MFMA GEMM: 512-thr/8-wave blocks, one 64KB W staging ----------------
// 391 blocks x 8 waves = 3128 waves; wave gw owns 32-row chunk gw (3125 chunks, exact).
// 2 blocks/CU (128 KB LDS) -> 16 waves/CU. A-loads issued BEFORE the single barrier
// (drained by it for free); after the barrier every wave runs ds_read+MFMA+store
// independently. Single A buffer keeps VGPR ~R5 level for 4 waves/SIMD.
template <int POOL>
__global__ __launch_bounds__(512) void k_gemm_mfma(
    const unsigned short* __restrict__ X0, const unsigned short* __restrict__ X1,
    const unsigned short* __restrict__ Wtp, const float* __restrict__ bias,
    unsigned short* __restrict__ outp,
    const int* __restrict__ gid, float* __restrict__ gsum) {
    __shared__ unsigned short WS[D * 256];   // 64 KB
    const int tid = threadIdx.x;
    const int wave = tid >> 6, lane = tid & 63;
    const int lm = lane & 15, lg = lane >> 4;
    const int koff = 8 * lg;
    const int gw = blockIdx.x * 8 + wave;    // chunk id
    const bool act = (gw < N_CHUNKS);

    // A fragments (issued first; the staging barrier drains them for free)
    bf16x8 a[2][8];
    if (act) {
#pragma unroll
        for (int t2 = 0; t2 < 2; ++t2) {
            int arow = gw * 32 + t2 * 16 + lm;
#pragma unroll
            for (int ks = 0; ks < 4; ++ks)
                a[t2][ks] = *(const bf16x8*)(X0 + (size_t)arow * D + ks * 32 + koff);
#pragma unroll
            for (int ks = 0; ks < 4; ++ks)
                a[t2][4 + ks] = *(const bf16x8*)(X1 + (size_t)arow * D + ks * 32 + koff);
        }
    }

    // stage weights -> LDS (64 KB, 128 B/thread)
    {
        const u16x8* g = (const u16x8*)Wtp;
        u16x8* s = (u16x8*)WS;
#pragma unroll
        for (int i = 0; i < 8; ++i) s[i * 512 + tid] = g[i * 512 + tid];
    }
    __syncthreads();
    if (!act) return;

    f32x4 acc[2][8];
#pragma unroll
    for (int t2 = 0; t2 < 2; ++t2)
#pragma unroll
        for (int i = 0; i < 8; ++i) acc[t2][i] = (f32x4){0.f, 0.f, 0.f, 0.f};

#pragma unroll
    for (int ct = 0; ct < 8; ++ct) {
        bf16x8 b[8];
#pragma unroll
        for (int ks = 0; ks < 8; ++ks)
            b[ks] = *(const bf16x8*)&WS[((ct * 8 + ks) * 64 + lane) * 8];
#pragma unroll
        for (int ks = 0; ks < 8; ++ks) {
            acc[0][ct] = __builtin_amdgcn_mfma_f32_16x16x32_bf16(a[0][ks], b[ks], acc[0][ct], 0, 0, 0);
            acc[1][ct] = __builtin_amdgcn_mfma_f32_16x16x32_bf16(a[1][ks], b[ks], acc[1][ct], 0, 0, 0);
        }
    }

#pragma unroll
    for (int t2 = 0; t2 < 2; ++t2) {
        const int trow0 = gw * 32 + t2 * 16;
        if (POOL == 0) {
#pragma unroll
            for (int r = 0; r < 4; ++r) {
                int row = trow0 + 4 * lg + r;
                u16x8 pk;
#pragma unroll
                for (int ct = 0; ct < 8; ++ct) {
                    float v = acc[t2][ct][r] + bias[ct * 16 + lm];
                    pk[ct] = f2bf(fmaxf(v, 0.f));
                }
                *(u16x8*)(outp + (size_t)row * D + lm * 8) = pk;
            }
        } else {
            int g[4];
#pragma unroll
            for (int r = 0; r < 4; ++r)
                g[r] = gid[trow0 + 4 * lg + r];
#pragma unroll
            for (int ct = 0; ct < 8; ++ct) {
                int c = ct * 16 + lm;
                float bia = bias[c];
                float run = 0.f; int curg = -1;
#pragma unroll
                for (int r = 0; r < 4; ++r) {
                    float v = fmaxf(acc[t2][ct][r] + bia, 0.f);
                    if (g[r] != curg) {
                        if (curg >= 0) atomicAdd(&gsum[curg * D + c], run);
                        curg = g[r]; run = v;
                    } else {
                        run += v;
                    }
                }
                if (curg >= 0) atomicAdd(&gsum[curg * D + c], run);
            }
        }
    }
}

// ---------------- final divide ----------------
__global__ void k_final(const float* __restrict__ gsum, const int* __restrict__ gcnt,
                        float* __restrict__ out) {
    int i = blockIdx.x * blockDim.x + threadIdx.x;
    if (i < NUM_GRAPHS * D) {
        int g = i >> 7;
        int c = gcnt[g];
        out[i] = gsum[i] / (float)(c > 0 ? c : 1);
    }
}

// ---------------- launch ----------------
extern "C" void kernel_launch(void* const* d_in, const int* in_sizes, int n_in,
                              void* d_out, int out_size, void* d_ws, size_t ws_size,
                              hipStream_t stream) {
    const float* h   = (const float*)d_in[0];
    const float* W1s = (const float*)d_in[1];
    const float* W1n = (const float*)d_in[2];
    const float* b1  = (const float*)d_in[3];
    const float* W2s = (const float*)d_in[4];
    const float* W2n = (const float*)d_in[5];
    const float* b2  = (const float*)d_in[6];
    const int* src   = (const int*)d_in[7];
    const int* dst   = (const int*)d_in[8];
    const int* gids  = (const int*)d_in[9];
    float* out = (float*)d_out;
    char* ws = (char*)d_ws;

    size_t off = 0;
    auto alloc = [&](size_t bytes) {
        size_t o = off;
        off = (off + bytes + 255) & ~(size_t)255;
        return o;
    };
    // zeroed region (one memset)
    size_t z0         = off;
    size_t gcur_off   = alloc((size_t)NB * 4);
    size_t gsum_off   = alloc((size_t)NUM_GRAPHS * D * 4);
    size_t zlen       = off - z0;
    size_t gcnt_off   = alloc((size_t)NUM_GRAPHS * 4);
    size_t rs_off     = alloc((size_t)N_NODES * 4);
    size_t rl_off     = alloc((size_t)N_NODES * 4);
    size_t bin_off    = alloc((size_t)NB * BUCKET_CAP * 4);
    size_t adj_off    = alloc((size_t)NB * BUCKET_CAP * 4);
    size_t hb_off     = alloc((size_t)N_NODES * D * 2);   // h bf16
    size_t hn_off     = alloc((size_t)N_NODES * D * 2);   // neigh agg bf16 (reused layer2)
    size_t h1_off     = alloc((size_t)N_NODES * D * 2);   // layer-1 out (permuted) bf16
    size_t wt1_off    = alloc((size_t)D * 256 * 2);
    size_t wt2_off    = alloc((size_t)D * 256 * 2);
    (void)ws_size;

    int*   gcur      = (int*)(ws + gcur_off);
    int*   gcnt      = (int*)(ws + gcnt_off);
    float* gsum      = (float*)(ws + gsum_off);
    int*   row_start = (int*)(ws + rs_off);
    int*   row_len   = (int*)(ws + rl_off);
    unsigned int* binned = (unsigned int*)(ws + bin_off);
    int*   adj       = (int*)(ws + adj_off);
    unsigned short* hb  = (unsigned short*)(ws + hb_off);
    unsigned short* hn  = (unsigned short*)(ws + hn_off);
    unsigned short* h1p = (unsigned short*)(ws + h1_off);
    unsigned short* Wt1 = (unsigned short*)(ws + wt1_off);
    unsigned short* Wt2 = (unsigned short*)(ws + wt2_off);

    hipMemsetAsync(ws + z0, 0, zlen, stream);

    const int nbin_blocks = (N_EDGES + EPB - 1) / EPB;   // 196

    k_binplace<<<nbin_blocks, 256, 0, stream>>>(src, dst, gcur, binned);
    k_fill2<<<NB, 256, 0, stream>>>(binned, gcur, adj, row_start, row_len);
    k_gcnt_bs<<<1, 128, 0, stream>>>(gids, gcnt);

    k_cast_h<<<(N_NODES * (D / 8) + 255) / 256, 256, 0, stream>>>(h, hb);
    k_prep_w1<<<(D * 256 + 255) / 256, 256, 0, stream>>>(W1s, W1n, Wt1);
    k_prep_w2<<<(D * 256 + 255) / 256, 256, 0, stream>>>(W2s, W2n, Wt2);

    const int agg_blocks  = (N_NODES + 15) / 16;    // 6250

    // layer 1
    k_agg_bf<<<agg_blocks, 256, 0, stream>>>(hb, row_start, row_len, adj, hn);
    k_gemm_mfma<0><<<GEMM_BLOCKS, 512, 0, stream>>>(hb, hn, Wt1, b1, h1p, nullptr, nullptr);
    // layer 2 (pool fused into epilogue)
    k_agg_bf<<<agg_blocks, 256, 0, stream>>>(h1p, row_start, row_len, adj, hn);
    k_gemm_mfma<1><<<GEMM_BLOCKS, 512, 0, stream>>>(h1p, hn, Wt2, b2, nullptr, gids, gsum);

    k_final<<<(NUM_GRAPHS * D + 255) / 256, 256, 0, stream>>>(gsum, gcnt, out);
}